// Round 20
// baseline (131.207 us; speedup 1.0000x reference)
//
#include <hip/hip_runtime.h>
#include <hip/hip_fp16.h>
#include <math.h>

#define DH 128
#define CAPW 128
#define GRPS 2
#define NSUB 64
#define SUPER (NSUB * 1024)    // 65536: edge-share super-block (hist & scatter MUST match)
#define HW4 12800              // packed hist words: supports n <= 51200 (50KB LDS)
#define SCHUNK 25600           // scatter cursor chunk (covers n/GRPS = 25000; 100KB LDS)

typedef _Float16 f16x8 __attribute__((ext_vector_type(8)));
typedef float    f32x4 __attribute__((ext_vector_type(4)));

__device__ __forceinline__ float waveSum(float x) {
    #pragma unroll
    for (int m = 32; m; m >>= 1) x += __shfl_xor(x, m);
    return x;
}
__device__ __forceinline__ unsigned waveSumU(unsigned x) {
    #pragma unroll
    for (int m = 32; m; m >>= 1) x += __shfl_xor(x, m);
    return x;
}

__device__ __forceinline__ float edgeW(float ui, float vd, float ab) {
    float C = fmaxf(ui + ab, 0.f);
    float lg = ui + vd + ab;
    lg = lg >= 0.f ? lg : 0.01f * lg;
    return __expf(fminf(lg - C, 10.f));
}

// K1: MFMA GEMM: h = x@W + b. 64 rows/block, 4 waves; wave w owns rows 16w..16w+15.
// Also zeroes the scan's ready[] flags (block 0).
__global__ __launch_bounds__(256) void k_matmul(
    const float* __restrict__ x, const float* __restrict__ Wg,
    const float* __restrict__ bg, const float* __restrict__ ag,
    __half2* __restrict__ h2, float* __restrict__ u, float* __restrict__ v,
    unsigned* __restrict__ ready, int n)
{
    __shared__ __half2 Wtp[128][68];   // Wtp[c][k2] = {W[2k2][c], W[2k2+1][c]}
    __shared__ __half2 Xs2[64][68];    // in: x rows (fp16 k-pairs); out: h rows
    __shared__ float as_s[128], ad_s[128];
    int t = threadIdx.x;
    int row0 = blockIdx.x * 64;
    if (blockIdx.x == 0) ready[t] = 0u;   // reset lookback flags each launch

    const float4* W4 = (const float4*)Wg;
    for (int i = t; i < 2048; i += 256) {      // i = k2*32 + c4
        int k2 = i >> 5, c4 = i & 31;
        float4 a = W4[(2 * k2) * 32 + c4];
        float4 b = W4[(2 * k2 + 1) * 32 + c4];
        Wtp[c4 * 4 + 0][k2] = __floats2half2_rn(a.x, b.x);
        Wtp[c4 * 4 + 1][k2] = __floats2half2_rn(a.y, b.y);
        Wtp[c4 * 4 + 2][k2] = __floats2half2_rn(a.z, b.z);
        Wtp[c4 * 4 + 3][k2] = __floats2half2_rn(a.w, b.w);
    }
    const float4* x4 = (const float4*)x;
    for (int i = t; i < 2048; i += 256) {      // i = r*32 + c4
        int r = i >> 5, c4 = i & 31;
        int gr = row0 + r;
        float4 xv = (gr < n) ? x4[(size_t)gr * 32 + c4] : float4{0.f, 0.f, 0.f, 0.f};
        Xs2[r][c4 * 2]     = __floats2half2_rn(xv.x, xv.y);
        Xs2[r][c4 * 2 + 1] = __floats2half2_rn(xv.z, xv.w);
    }
    if (t < 128) { as_s[t] = ag[t]; ad_s[t] = ag[128 + t]; }
    __syncthreads();

    int wv = t >> 6, l = t & 63;
    int m = l & 15, g = l >> 4;
    int r0 = wv * 16;

    f16x8 afr[4];
    #pragma unroll
    for (int ks = 0; ks < 4; ++ks)
        afr[ks] = *(const f16x8*)&Xs2[r0 + m][ks * 16 + g * 4];

    f32x4 accv[8];
    #pragma unroll
    for (int j = 0; j < 8; ++j) accv[j] = (f32x4){0.f, 0.f, 0.f, 0.f};

    #pragma unroll
    for (int j = 0; j < 8; ++j) {               // col tile n0 = j*16
        #pragma unroll
        for (int ks = 0; ks < 4; ++ks) {
            f16x8 bfr = *(const f16x8*)&Wtp[j * 16 + m][ks * 16 + g * 4];
            accv[j] = __builtin_amdgcn_mfma_f32_16x16x32_f16(afr[ks], bfr, accv[j], 0, 0, 0);
        }
    }
    __syncthreads();   // Xs2 x-data fully consumed; reuse as h-row staging

    __half* hs = (__half*)Xs2;                  // row stride 136 half (272 B)
    #pragma unroll
    for (int j = 0; j < 8; ++j) {
        int cc = j * 16 + m;
        float bv = bg[cc];
        #pragma unroll
        for (int rg = 0; rg < 4; ++rg) {
            int rr = r0 + g * 4 + rg;
            hs[rr * 136 + cc] = __float2half_rn(accv[j][rg] + bv);
        }
    }
    __syncthreads();

    // coalesced h store
    for (int i = t; i < 1024; i += 256) {       // i = r*16 + c8 (16B chunks)
        int r = i >> 4, c8 = i & 15;
        int gr = row0 + r;
        if (gr < n)
            ((float4*)h2)[(size_t)gr * 16 + c8] =
                *(const float4*)((const char*)Xs2 + r * 272 + c8 * 16);
    }
    // u,v: 4 threads per row, 32 cols each, reduce over lanes {1,2}
    int ur = t >> 2, useg = t & 3;
    float su = 0.f, sv = 0.f;
    const __half2* xr = &Xs2[ur][useg * 16];
    #pragma unroll
    for (int j = 0; j < 16; ++j) {
        float2 f = __half22float2(xr[j]);
        int k = useg * 32 + 2 * j;
        su += f.x * as_s[k] + f.y * as_s[k + 1];
        sv += f.x * ad_s[k] + f.y * ad_s[k + 1];
    }
    su += __shfl_xor(su, 1); su += __shfl_xor(su, 2);
    sv += __shfl_xor(sv, 1); sv += __shfl_xor(sv, 2);
    int gr = row0 + ur;
    if (useg == 0 && gr < n) { u[gr] = su; v[gr] = sv; }
}

// K1b: SINGLE-PASS histogram, byte-packed LDS counters (4 nodes/word). Grid =
// NSUB blocks x 1024 thr; block `sub` counts its strided edge share
// (e = sub*1024+t step SUPER — MUST match k_scatter). Per-sub per-node count
// max ~10 << 255 -> no byte overflow. Flush = direct word stores.
__global__ __launch_bounds__(1024) void k_hist(
    const int* __restrict__ ei, int E, int n, unsigned char* __restrict__ hsub)
{
    __shared__ unsigned h8[HW4];
    int sub = blockIdx.x;
    int t = threadIdx.x;
    int nw = (n + 3) >> 2;
    for (int i = t; i < nw; i += 1024) h8[i] = 0u;
    __syncthreads();
    for (int e = sub * 1024 + t; e < E; e += SUPER) {
        int s = ei[e];
        atomicAdd(&h8[s >> 2], 1u << ((s & 3) * 8));
    }
    __syncthreads();
    unsigned* hrow = (unsigned*)(hsub + (size_t)sub * n);   // n % 4 == 0
    for (int i = t; i < nw; i += 1024) hrow[i] = h8[i];
}

// K2: SINGLE-KERNEL scan (decoupled lookback). Per-node totals + per-sub uchar
// deltas basepu (slot 0 = self-loop; run <= deg+1 ~70 << 255), local scan,
// publish inclusive total with ready bit, poll predecessors, wave-reduce bases.
// Self-loop: edst[off[idx]] = idx.
__global__ __launch_bounds__(256) void k_scan(
    const unsigned char* __restrict__ hsub, unsigned* __restrict__ ready,
    unsigned* __restrict__ off, unsigned char* __restrict__ basepu,
    int* __restrict__ edst, int n)
{
    __shared__ unsigned s[256];
    __shared__ unsigned wred[4];
    int t = threadIdx.x, bid = blockIdx.x, idx = bid * 256 + t;

    unsigned run = 0u;
    if (idx < n) {
        run = 1u;                                  // slot 0: self-loop
        for (int sb = 0; sb < NSUB; ++sb) {
            basepu[(size_t)sb * n + idx] = (unsigned char)run;
            run += hsub[(size_t)sb * n + idx];
        }
    }
    s[t] = run; __syncthreads();
    for (int d = 1; d < 256; d <<= 1) {
        unsigned xx = (t >= d) ? s[t - d] : 0u;
        __syncthreads();
        s[t] += xx;
        __syncthreads();
    }
    if (t == 255) {                               // publish inclusive block total
        __threadfence();
        atomicExch(&ready[bid], 0x80000000u | s[255]);
    }
    unsigned p = 0u;
    if (t < bid) {                                // poll predecessor t
        unsigned val;
        do { val = atomicAdd(&ready[t], 0u); } while (!(val & 0x80000000u));
        p = val & 0x7FFFFFFFu;
    }
    p = waveSumU(p);
    if ((t & 63) == 0) wred[t >> 6] = p;
    __syncthreads();
    unsigned base = wred[0] + wred[1] + wred[2] + wred[3];

    unsigned excl = s[t] - run + base;
    if (idx < n) {
        off[idx] = excl;
        if (idx == n - 1) off[n] = excl + run;
        edst[excl] = idx;                          // self-loop occupies slot 0
    }
}

// K4: atomic-free scatter, GRPS=2 node-range partitioned (each group's edst
// write region ~3.3MB fits a 4MB XCD L2 — confined writes, round-16 lesson).
// ei streamed GRPS times total (halved vs GRPS=4). LDS cursors (100KB, 1
// block/CU) = off + basepu delta; edge share per sub MUST equal k_hist's.
// Grid = GRPS*NSUB = 128.
__global__ __launch_bounds__(1024) void k_scatter(
    const int* __restrict__ ei, int E, int n,
    const unsigned* __restrict__ off, const unsigned char* __restrict__ basepu,
    int* __restrict__ edst)
{
    __shared__ unsigned cur[SCHUNK];
    int grp = blockIdx.x & (GRPS - 1);
    int sub = blockIdx.x / GRPS;
    int t = threadIdx.x;
    int lo = (int)((long long)grp * n / GRPS);
    int hi = (int)((long long)(grp + 1) * n / GRPS);
    const unsigned char* bps = basepu + (size_t)sub * n;
    for (int base = lo; base < hi; base += SCHUNK) {
        int clen = min(SCHUNK, hi - base);
        for (int i = t; i < clen; i += 1024)
            cur[i] = off[base + i] + bps[base + i];
        __syncthreads();
        for (int e = sub * 1024 + t; e < E; e += SUPER) {
            int s = ei[e];
            int d = ei[E + e];               // coalesced, unconditional
            if (s >= base && s < base + clen) {
                unsigned p = atomicAdd(&cur[s - base], 1u);   // LDS atomic only
                edst[p] = d;
            }
        }
        __syncthreads();
    }
}

// K5: one WAVE per node, 4 nodes/block, barrier-free (round-18 version — the
// dst-sort variant was null on FETCH and cost VALU). Pass1: edst read + v[d]
// gather + edgeW, stash {d, w} in LDS. Pass2 (deg<=CAPW, always in practice):
// stash padded to multiple of 16 -> branch-free 4-deep gather pipeline.
__global__ __launch_bounds__(256) void k_agg(
    const int* __restrict__ edst, const unsigned* __restrict__ off,
    const __half2* __restrict__ h2, const float* __restrict__ u,
    const float* __restrict__ v, const float* __restrict__ ab_p,
    float* __restrict__ out, int n)
{
    __shared__ float ex_s[4][CAPW];
    __shared__ int   ds_s[4][CAPW];
    int t = threadIdx.x;
    int wave = t >> 6, lane = t & 63;
    int i = blockIdx.x * 4 + wave;
    if (i >= n) return;
    unsigned s0 = off[i];
    int deg = (int)(off[i + 1] - s0);
    float ab = ab_p[0];
    float ui = u[i];

    float sm = 0.f;
    for (int e = lane; e < deg; e += 64) {
        int d = edst[s0 + e];
        float w = edgeW(ui, v[d], ab);
        if (e < CAPW) { ds_s[wave][e] = d; ex_s[wave][e] = w; }
        sm += w;
    }
    sm = waveSum(sm);
    float inv = 1.f / sm;

    int g = lane >> 4, gl = lane & 15;
    float acc[8];

    if (deg <= CAPW) {
        int degp = (deg + 15) & ~15;
        for (int e = deg + lane; e < degp; e += 64) { ds_s[wave][e] = 0; ex_s[wave][e] = 0.f; }

        __half2 a4[4][4];
        #pragma unroll
        for (int q = 0; q < 4; ++q)
            #pragma unroll
            for (int k = 0; k < 4; ++k) a4[q][k] = __float2half2_rn(0.f);

        for (int e0 = g; e0 < degp; e0 += 16) {
            #pragma unroll
            for (int q = 0; q < 4; ++q) {
                int e = e0 + q * 4;
                int d = ds_s[wave][e];
                __half2 wh = __float2half2_rn(ex_s[wave][e]);
                float4 raw = ((const float4*)(h2 + (size_t)d * 64))[gl];
                const __half2* hp = (const __half2*)&raw;
                #pragma unroll
                for (int k = 0; k < 4; ++k) a4[q][k] = __hfma2(wh, hp[k], a4[q][k]);
            }
        }
        #pragma unroll
        for (int k = 0; k < 4; ++k) {
            float2 f0 = __half22float2(a4[0][k]);
            float2 f1 = __half22float2(a4[1][k]);
            float2 f2 = __half22float2(a4[2][k]);
            float2 f3 = __half22float2(a4[3][k]);
            acc[2 * k]     = (f0.x + f1.x) + (f2.x + f3.x);
            acc[2 * k + 1] = (f0.y + f1.y) + (f2.y + f3.y);
        }
    } else {
        __half2 accA[4], accB[4];
        #pragma unroll
        for (int k = 0; k < 4; ++k) { accA[k] = __float2half2_rn(0.f); accB[k] = __float2half2_rn(0.f); }
        for (int e = g; e < deg; e += 8) {
            {
                float w; int d;
                if (e < CAPW) { w = ex_s[wave][e]; d = ds_s[wave][e]; }
                else          { d = edst[s0 + e]; w = edgeW(ui, v[d], ab); }
                __half2 wh = __float2half2_rn(w);
                float4 raw = ((const float4*)(h2 + (size_t)d * 64))[gl];
                const __half2* hp = (const __half2*)&raw;
                #pragma unroll
                for (int k = 0; k < 4; ++k) accA[k] = __hfma2(wh, hp[k], accA[k]);
            }
            int e2 = e + 4;
            if (e2 < deg) {
                float w; int d;
                if (e2 < CAPW) { w = ex_s[wave][e2]; d = ds_s[wave][e2]; }
                else           { d = edst[s0 + e2]; w = edgeW(ui, v[d], ab); }
                __half2 wh = __float2half2_rn(w);
                float4 raw = ((const float4*)(h2 + (size_t)d * 64))[gl];
                const __half2* hp = (const __half2*)&raw;
                #pragma unroll
                for (int k = 0; k < 4; ++k) accB[k] = __hfma2(wh, hp[k], accB[k]);
            }
        }
        #pragma unroll
        for (int k = 0; k < 4; ++k) {
            float2 fa = __half22float2(accA[k]);
            float2 fb = __half22float2(accB[k]);
            acc[2 * k]     = fa.x + fb.x;
            acc[2 * k + 1] = fa.y + fb.y;
        }
    }

    #pragma unroll
    for (int k = 0; k < 8; ++k) {
        acc[k] += __shfl_xor(acc[k], 16);
        acc[k] += __shfl_xor(acc[k], 32);
    }
    if (g == 0) {
        float o[8];
        #pragma unroll
        for (int k = 0; k < 8; ++k) {
            float z = acc[k] * inv;
            o[k] = z > 0.f ? z : expm1f(z);
        }
        float4* orow = (float4*)(out + (size_t)i * DH);
        orow[gl * 2]     = float4{o[0], o[1], o[2], o[3]};
        orow[gl * 2 + 1] = float4{o[4], o[5], o[6], o[7]};
    }
}

extern "C" void kernel_launch(void* const* d_in, const int* in_sizes, int n_in,
                              void* d_out, int out_size, void* d_ws, size_t ws_size,
                              hipStream_t stream) {
    const float* x  = (const float*)d_in[0];
    const int*   ei = (const int*)d_in[1];
    const float* W  = (const float*)d_in[2];
    const float* b  = (const float*)d_in[3];
    const float* a  = (const float*)d_in[4];
    const float* ab = (const float*)d_in[5];
    float* out = (float*)d_out;
    int n  = in_sizes[0] / DH;    // 50000 (byte-packed LDS + SCHUNK require n <= 51200)
    int E  = in_sizes[1] / 2;
    int ET = E + n;

    char* w = (char*)d_ws;
    __half2*       h2     = (__half2*)w;        w += (size_t)n * DH * 2;
    float*         u      = (float*)w;          w += (size_t)n * 4;
    float*         v      = (float*)w;          w += (size_t)n * 4;
    unsigned*      off    = (unsigned*)w;       w += (size_t)(n + 1) * 4 + 4;
    int*           edst   = (int*)w;            w += (size_t)ET * 4;
    unsigned*      ready  = (unsigned*)w;       w += 4096;
    unsigned char* hsub   = (unsigned char*)w;  w += (size_t)NSUB * n;
    unsigned char* basepu = (unsigned char*)w;  w += (size_t)NSUB * n;

    int nb = (n + 63) / 64;
    k_matmul<<<nb, 256, 0, stream>>>(x, W, b, a, h2, u, v, ready, n);

    // single-pass histogram: grid = NSUB (edge-share subs)
    k_hist<<<NSUB, 1024, 0, stream>>>(ei, E, n, hsub);

    int B = (n + 255) / 256;
    k_scan<<<B, 256, 0, stream>>>(hsub, ready, off, basepu, edst, n);

    // node-range partitioned scatter: grid = GRPS*NSUB = 128, shares match k_hist
    k_scatter<<<GRPS * NSUB, 1024, 0, stream>>>(ei, E, n, off, basepu, edst);

    k_agg<<<(n + 3) / 4, 256, 0, stream>>>(edst, off, h2, u, v, ab, out, n);
}

// Round 21
// 127.918 us; speedup vs baseline: 1.0257x; 1.0257x over previous
//
#include <hip/hip_runtime.h>
#include <hip/hip_fp16.h>
#include <math.h>

#define DH 128
#define CAPW 128
#define GRPS 4
#define NSUB 64
#define SUPER (NSUB * 1024)    // 65536: edge-share super-block (hist & scatter MUST match)
#define HW4 12800              // packed hist words: supports n <= 51200 (50KB LDS)
#define HCHUNK 12800           // scatter cursor chunk (covers n/GRPS = 12500)

typedef _Float16 f16x8 __attribute__((ext_vector_type(8)));
typedef float    f32x4 __attribute__((ext_vector_type(4)));

__device__ __forceinline__ float waveSum(float x) {
    #pragma unroll
    for (int m = 32; m; m >>= 1) x += __shfl_xor(x, m);
    return x;
}
__device__ __forceinline__ unsigned waveSumU(unsigned x) {
    #pragma unroll
    for (int m = 32; m; m >>= 1) x += __shfl_xor(x, m);
    return x;
}

__device__ __forceinline__ float edgeW(float ui, float vd, float ab) {
    float C = fmaxf(ui + ab, 0.f);
    float lg = ui + vd + ab;
    lg = lg >= 0.f ? lg : 0.01f * lg;
    return __expf(fminf(lg - C, 10.f));
}

// K1: MFMA GEMM: h = x@W + b. 64 rows/block, 4 waves; wave w owns rows 16w..16w+15.
// Also zeroes the scan's ready[] flags (block 0).
__global__ __launch_bounds__(256) void k_matmul(
    const float* __restrict__ x, const float* __restrict__ Wg,
    const float* __restrict__ bg, const float* __restrict__ ag,
    __half2* __restrict__ h2, float* __restrict__ u, float* __restrict__ v,
    unsigned* __restrict__ ready, int n)
{
    __shared__ __half2 Wtp[128][68];   // Wtp[c][k2] = {W[2k2][c], W[2k2+1][c]}
    __shared__ __half2 Xs2[64][68];    // in: x rows (fp16 k-pairs); out: h rows
    __shared__ float as_s[128], ad_s[128];
    int t = threadIdx.x;
    int row0 = blockIdx.x * 64;
    if (blockIdx.x == 0) ready[t] = 0u;   // reset lookback flags each launch

    const float4* W4 = (const float4*)Wg;
    for (int i = t; i < 2048; i += 256) {      // i = k2*32 + c4
        int k2 = i >> 5, c4 = i & 31;
        float4 a = W4[(2 * k2) * 32 + c4];
        float4 b = W4[(2 * k2 + 1) * 32 + c4];
        Wtp[c4 * 4 + 0][k2] = __floats2half2_rn(a.x, b.x);
        Wtp[c4 * 4 + 1][k2] = __floats2half2_rn(a.y, b.y);
        Wtp[c4 * 4 + 2][k2] = __floats2half2_rn(a.z, b.z);
        Wtp[c4 * 4 + 3][k2] = __floats2half2_rn(a.w, b.w);
    }
    const float4* x4 = (const float4*)x;
    for (int i = t; i < 2048; i += 256) {      // i = r*32 + c4
        int r = i >> 5, c4 = i & 31;
        int gr = row0 + r;
        float4 xv = (gr < n) ? x4[(size_t)gr * 32 + c4] : float4{0.f, 0.f, 0.f, 0.f};
        Xs2[r][c4 * 2]     = __floats2half2_rn(xv.x, xv.y);
        Xs2[r][c4 * 2 + 1] = __floats2half2_rn(xv.z, xv.w);
    }
    if (t < 128) { as_s[t] = ag[t]; ad_s[t] = ag[128 + t]; }
    __syncthreads();

    int wv = t >> 6, l = t & 63;
    int m = l & 15, g = l >> 4;
    int r0 = wv * 16;

    f16x8 afr[4];
    #pragma unroll
    for (int ks = 0; ks < 4; ++ks)
        afr[ks] = *(const f16x8*)&Xs2[r0 + m][ks * 16 + g * 4];

    f32x4 accv[8];
    #pragma unroll
    for (int j = 0; j < 8; ++j) accv[j] = (f32x4){0.f, 0.f, 0.f, 0.f};

    #pragma unroll
    for (int j = 0; j < 8; ++j) {               // col tile n0 = j*16
        #pragma unroll
        for (int ks = 0; ks < 4; ++ks) {
            f16x8 bfr = *(const f16x8*)&Wtp[j * 16 + m][ks * 16 + g * 4];
            accv[j] = __builtin_amdgcn_mfma_f32_16x16x32_f16(afr[ks], bfr, accv[j], 0, 0, 0);
        }
    }
    __syncthreads();   // Xs2 x-data fully consumed; reuse as h-row staging

    __half* hs = (__half*)Xs2;                  // row stride 136 half (272 B)
    #pragma unroll
    for (int j = 0; j < 8; ++j) {
        int cc = j * 16 + m;
        float bv = bg[cc];
        #pragma unroll
        for (int rg = 0; rg < 4; ++rg) {
            int rr = r0 + g * 4 + rg;
            hs[rr * 136 + cc] = __float2half_rn(accv[j][rg] + bv);
        }
    }
    __syncthreads();

    // coalesced h store
    for (int i = t; i < 1024; i += 256) {       // i = r*16 + c8 (16B chunks)
        int r = i >> 4, c8 = i & 15;
        int gr = row0 + r;
        if (gr < n)
            ((float4*)h2)[(size_t)gr * 16 + c8] =
                *(const float4*)((const char*)Xs2 + r * 272 + c8 * 16);
    }
    // u,v: 4 threads per row, 32 cols each, reduce over lanes {1,2}
    int ur = t >> 2, useg = t & 3;
    float su = 0.f, sv = 0.f;
    const __half2* xr = &Xs2[ur][useg * 16];
    #pragma unroll
    for (int j = 0; j < 16; ++j) {
        float2 f = __half22float2(xr[j]);
        int k = useg * 32 + 2 * j;
        su += f.x * as_s[k] + f.y * as_s[k + 1];
        sv += f.x * ad_s[k] + f.y * ad_s[k + 1];
    }
    su += __shfl_xor(su, 1); su += __shfl_xor(su, 2);
    sv += __shfl_xor(sv, 1); sv += __shfl_xor(sv, 2);
    int gr = row0 + ur;
    if (useg == 0 && gr < n) { u[gr] = su; v[gr] = sv; }
}

// K1b: SINGLE-PASS histogram, byte-packed LDS counters (4 nodes/word). Grid =
// NSUB blocks x 1024 thr; block `sub` counts its strided edge share
// (e = sub*1024+t step SUPER — MUST match k_scatter). Per-sub per-node count
// max ~10 << 255 -> no byte overflow. Flush = direct word stores.
__global__ __launch_bounds__(1024) void k_hist(
    const int* __restrict__ ei, int E, int n, unsigned char* __restrict__ hsub)
{
    __shared__ unsigned h8[HW4];
    int sub = blockIdx.x;
    int t = threadIdx.x;
    int nw = (n + 3) >> 2;
    for (int i = t; i < nw; i += 1024) h8[i] = 0u;
    __syncthreads();
    for (int e = sub * 1024 + t; e < E; e += SUPER) {
        int s = ei[e];
        atomicAdd(&h8[s >> 2], 1u << ((s & 3) * 8));
    }
    __syncthreads();
    unsigned* hrow = (unsigned*)(hsub + (size_t)sub * n);   // n % 4 == 0
    for (int i = t; i < nw; i += 1024) hrow[i] = h8[i];
}

// K2: SINGLE-KERNEL scan (decoupled lookback). Per-node totals + per-sub uchar
// deltas basepu (slot 0 = self-loop; run <= deg+1 ~70 << 255), local scan,
// publish inclusive total with ready bit, poll predecessors, wave-reduce bases.
// Self-loop: edst[off[idx]] = idx.
__global__ __launch_bounds__(256) void k_scan(
    const unsigned char* __restrict__ hsub, unsigned* __restrict__ ready,
    unsigned* __restrict__ off, unsigned char* __restrict__ basepu,
    int* __restrict__ edst, int n)
{
    __shared__ unsigned s[256];
    __shared__ unsigned wred[4];
    int t = threadIdx.x, bid = blockIdx.x, idx = bid * 256 + t;

    unsigned run = 0u;
    if (idx < n) {
        run = 1u;                                  // slot 0: self-loop
        for (int sb = 0; sb < NSUB; ++sb) {
            basepu[(size_t)sb * n + idx] = (unsigned char)run;
            run += hsub[(size_t)sb * n + idx];
        }
    }
    s[t] = run; __syncthreads();
    for (int d = 1; d < 256; d <<= 1) {
        unsigned xx = (t >= d) ? s[t - d] : 0u;
        __syncthreads();
        s[t] += xx;
        __syncthreads();
    }
    if (t == 255) {                               // publish inclusive block total
        __threadfence();
        atomicExch(&ready[bid], 0x80000000u | s[255]);
    }
    unsigned p = 0u;
    if (t < bid) {                                // poll predecessor t
        unsigned val;
        do { val = atomicAdd(&ready[t], 0u); } while (!(val & 0x80000000u));
        p = val & 0x7FFFFFFFu;
    }
    p = waveSumU(p);
    if ((t & 63) == 0) wred[t >> 6] = p;
    __syncthreads();
    unsigned base = wred[0] + wred[1] + wred[2] + wred[3];

    unsigned excl = s[t] - run + base;
    if (idx < n) {
        off[idx] = excl;
        if (idx == n - 1) off[n] = excl + run;
        edst[excl] = idx;                          // self-loop occupies slot 0
    }
}

// K4: atomic-free scatter, GRPS=4 node-range partitioned (confines writes to a
// contiguous L2-resident region — proven load-bearing in rounds 3/16/20).
// LDS cursors = off + basepu delta; edge share per (grp,sub) MUST equal
// k_hist's share. Grid = GRPS*NSUB.
__global__ __launch_bounds__(1024) void k_scatter(
    const int* __restrict__ ei, int E, int n,
    const unsigned* __restrict__ off, const unsigned char* __restrict__ basepu,
    int* __restrict__ edst)
{
    __shared__ unsigned cur[HCHUNK];
    int grp = blockIdx.x & (GRPS - 1);
    int sub = blockIdx.x / GRPS;
    int t = threadIdx.x;
    int lo = (int)((long long)grp * n / GRPS);
    int hi = (int)((long long)(grp + 1) * n / GRPS);
    const unsigned char* bps = basepu + (size_t)sub * n;
    for (int base = lo; base < hi; base += HCHUNK) {
        int clen = min(HCHUNK, hi - base);
        for (int i = t; i < clen; i += 1024)
            cur[i] = off[base + i] + bps[base + i];
        __syncthreads();
        for (int e = sub * 1024 + t; e < E; e += SUPER) {
            int s = ei[e];
            int d = ei[E + e];               // coalesced, unconditional
            if (s >= base && s < base + clen) {
                unsigned p = atomicAdd(&cur[s - base], 1u);   // LDS atomic only
                edst[p] = d;
            }
        }
        __syncthreads();
    }
}

// K5: one WAVE per node, 4 nodes/block, barrier-free. Pass1: edst read + v[d]
// gather + edgeW, stash {d, w} in LDS. Pass2 (deg<=CAPW, always in practice):
// stash padded to multiple of 16 -> branch-free 4-deep gather pipeline
// (4 independent dwordx4 in flight per lane, 4 fp16 accumulator sets).
__global__ __launch_bounds__(256) void k_agg(
    const int* __restrict__ edst, const unsigned* __restrict__ off,
    const __half2* __restrict__ h2, const float* __restrict__ u,
    const float* __restrict__ v, const float* __restrict__ ab_p,
    float* __restrict__ out, int n)
{
    __shared__ float ex_s[4][CAPW];
    __shared__ int   ds_s[4][CAPW];
    int t = threadIdx.x;
    int wave = t >> 6, lane = t & 63;
    int i = blockIdx.x * 4 + wave;
    if (i >= n) return;
    unsigned s0 = off[i];
    int deg = (int)(off[i + 1] - s0);
    float ab = ab_p[0];
    float ui = u[i];

    float sm = 0.f;
    for (int e = lane; e < deg; e += 64) {
        int d = edst[s0 + e];
        float w = edgeW(ui, v[d], ab);
        if (e < CAPW) { ds_s[wave][e] = d; ex_s[wave][e] = w; }
        sm += w;
    }
    sm = waveSum(sm);
    float inv = 1.f / sm;

    int g = lane >> 4, gl = lane & 15;
    float acc[8];

    if (deg <= CAPW) {
        int degp = (deg + 15) & ~15;
        for (int e = deg + lane; e < degp; e += 64) { ds_s[wave][e] = 0; ex_s[wave][e] = 0.f; }

        __half2 a4[4][4];
        #pragma unroll
        for (int q = 0; q < 4; ++q)
            #pragma unroll
            for (int k = 0; k < 4; ++k) a4[q][k] = __float2half2_rn(0.f);

        for (int e0 = g; e0 < degp; e0 += 16) {
            #pragma unroll
            for (int q = 0; q < 4; ++q) {
                int e = e0 + q * 4;
                int d = ds_s[wave][e];
                __half2 wh = __float2half2_rn(ex_s[wave][e]);
                float4 raw = ((const float4*)(h2 + (size_t)d * 64))[gl];
                const __half2* hp = (const __half2*)&raw;
                #pragma unroll
                for (int k = 0; k < 4; ++k) a4[q][k] = __hfma2(wh, hp[k], a4[q][k]);
            }
        }
        #pragma unroll
        for (int k = 0; k < 4; ++k) {
            float2 f0 = __half22float2(a4[0][k]);
            float2 f1 = __half22float2(a4[1][k]);
            float2 f2 = __half22float2(a4[2][k]);
            float2 f3 = __half22float2(a4[3][k]);
            acc[2 * k]     = (f0.x + f1.x) + (f2.x + f3.x);
            acc[2 * k + 1] = (f0.y + f1.y) + (f2.y + f3.y);
        }
    } else {
        __half2 accA[4], accB[4];
        #pragma unroll
        for (int k = 0; k < 4; ++k) { accA[k] = __float2half2_rn(0.f); accB[k] = __float2half2_rn(0.f); }
        for (int e = g; e < deg; e += 8) {
            {
                float w; int d;
                if (e < CAPW) { w = ex_s[wave][e]; d = ds_s[wave][e]; }
                else          { d = edst[s0 + e]; w = edgeW(ui, v[d], ab); }
                __half2 wh = __float2half2_rn(w);
                float4 raw = ((const float4*)(h2 + (size_t)d * 64))[gl];
                const __half2* hp = (const __half2*)&raw;
                #pragma unroll
                for (int k = 0; k < 4; ++k) accA[k] = __hfma2(wh, hp[k], accA[k]);
            }
            int e2 = e + 4;
            if (e2 < deg) {
                float w; int d;
                if (e2 < CAPW) { w = ex_s[wave][e2]; d = ds_s[wave][e2]; }
                else           { d = edst[s0 + e2]; w = edgeW(ui, v[d], ab); }
                __half2 wh = __float2half2_rn(w);
                float4 raw = ((const float4*)(h2 + (size_t)d * 64))[gl];
                const __half2* hp = (const __half2*)&raw;
                #pragma unroll
                for (int k = 0; k < 4; ++k) accB[k] = __hfma2(wh, hp[k], accB[k]);
            }
        }
        #pragma unroll
        for (int k = 0; k < 4; ++k) {
            float2 fa = __half22float2(accA[k]);
            float2 fb = __half22float2(accB[k]);
            acc[2 * k]     = fa.x + fb.x;
            acc[2 * k + 1] = fa.y + fb.y;
        }
    }

    #pragma unroll
    for (int k = 0; k < 8; ++k) {
        acc[k] += __shfl_xor(acc[k], 16);
        acc[k] += __shfl_xor(acc[k], 32);
    }
    if (g == 0) {
        float o[8];
        #pragma unroll
        for (int k = 0; k < 8; ++k) {
            float z = acc[k] * inv;
            o[k] = z > 0.f ? z : expm1f(z);
        }
        float4* orow = (float4*)(out + (size_t)i * DH);
        orow[gl * 2]     = float4{o[0], o[1], o[2], o[3]};
        orow[gl * 2 + 1] = float4{o[4], o[5], o[6], o[7]};
    }
}

extern "C" void kernel_launch(void* const* d_in, const int* in_sizes, int n_in,
                              void* d_out, int out_size, void* d_ws, size_t ws_size,
                              hipStream_t stream) {
    const float* x  = (const float*)d_in[0];
    const int*   ei = (const int*)d_in[1];
    const float* W  = (const float*)d_in[2];
    const float* b  = (const float*)d_in[3];
    const float* a  = (const float*)d_in[4];
    const float* ab = (const float*)d_in[5];
    float* out = (float*)d_out;
    int n  = in_sizes[0] / DH;    // 50000 (byte-packed LDS requires n <= 51200)
    int E  = in_sizes[1] / 2;
    int ET = E + n;

    char* w = (char*)d_ws;
    __half2*       h2     = (__half2*)w;        w += (size_t)n * DH * 2;
    float*         u      = (float*)w;          w += (size_t)n * 4;
    float*         v      = (float*)w;          w += (size_t)n * 4;
    unsigned*      off    = (unsigned*)w;       w += (size_t)(n + 1) * 4 + 4;
    int*           edst   = (int*)w;            w += (size_t)ET * 4;
    unsigned*      ready  = (unsigned*)w;       w += 4096;
    unsigned char* hsub   = (unsigned char*)w;  w += (size_t)NSUB * n;
    unsigned char* basepu = (unsigned char*)w;  w += (size_t)NSUB * n;

    int nb = (n + 63) / 64;
    k_matmul<<<nb, 256, 0, stream>>>(x, W, b, a, h2, u, v, ready, n);

    // single-pass histogram: grid = NSUB (edge-share subs)
    k_hist<<<NSUB, 1024, 0, stream>>>(ei, E, n, hsub);

    int B = (n + 255) / 256;
    k_scan<<<B, 256, 0, stream>>>(hsub, ready, off, basepu, edst, n);

    // node-range partitioned scatter: grid = GRPS*NSUB, shares match k_hist
    k_scatter<<<GRPS * NSUB, 1024, 0, stream>>>(ei, E, n, off, basepu, edst);

    k_agg<<<(n + 3) / 4, 256, 0, stream>>>(edst, off, h2, u, v, ab, out, n);
}